// Round 13
// baseline (3410.736 us; speedup 1.0000x reference)
//
#include <hip/hip_runtime.h>

typedef unsigned short u16;
typedef unsigned int u32;
typedef unsigned long long u64;
typedef __attribute__((ext_vector_type(8))) short bf16x8;
typedef __attribute__((ext_vector_type(8))) unsigned short u16x8;
typedef __attribute__((ext_vector_type(4))) unsigned short u16x4;
typedef __attribute__((ext_vector_type(4))) float f32x4;

#define DEVI static __device__ __forceinline__
#define MFMA __builtin_amdgcn_mfma_f32_16x16x32_bf16

constexpr int B = 32, S = 128, T = 64, H = 512, V = 32000;
constexpr int H4 = 4 * H;          // 2048
constexpr int TD = T - 1;          // 63 decoder steps
constexpr int MOUT = TD * B;       // 2016
constexpr int KOUT = 3 * H;        // 1536
constexpr int PAD_IDX = 1;

DEVI u16 f2bf(float f) {
  union { float f; unsigned u; } v; v.f = f;
  unsigned r = (v.u + 0x7fffu + ((v.u >> 16) & 1u)) >> 16;
  return (u16)r;
}
DEVI float bf2f(u16 h) {
  union { unsigned u; float f; } v; v.u = ((unsigned)h) << 16;
  return v.f;
}
DEVI float sigm(float x) { return 1.f / (1.f + __expf(-x)); }
DEVI float tanh_(float x) {
  float ax = fabsf(x);
  float e = __expf(-2.f * ax);
  float t = (1.f - e) / (1.f + e);
  return x < 0.f ? -t : t;
}
DEVI float tanhf_(float x) {
  float e = __expf(2.f * x);
  return 1.f - 2.f * __builtin_amdgcn_rcpf(e + 1.f);
}
DEVI int swz(int row, int k8) { return row * 32 + ((k8 ^ (row & 3)) << 3); }

DEVI u64 pack4u(const u16* p) {
  return (u64)p[0] | ((u64)p[1] << 16) | ((u64)p[2] << 32) | ((u64)p[3] << 48);
}
// data write-through to coherence point; returned old keeps vmcnt honest
DEVI u64 xstore(u16* p, u64 v) {
  return __hip_atomic_exchange((u64*)p, v, __ATOMIC_RELAXED,
                               __HIP_MEMORY_SCOPE_AGENT);
}
DEVI u64 xstore64(u64* p, u64 v) {
  return __hip_atomic_exchange(p, v, __ATOMIC_RELAXED,
                               __HIP_MEMORY_SCOPE_AGENT);
}
DEVI void sstore(unsigned* p, unsigned v) {
  __hip_atomic_exchange(p, v, __ATOMIC_RELAXED, __HIP_MEMORY_SCOPE_AGENT);
}
// poll with light backoff; loads only, 64B-strided slots
DEVI void poll_bo(unsigned* p, unsigned tgt) {
  int it = 0;
  long long t0 = (long long)__builtin_amdgcn_s_memrealtime();
  while (__hip_atomic_load(p, __ATOMIC_RELAXED, __HIP_MEMORY_SCOPE_AGENT) <
         tgt) {
    if (it < 4) {
      __builtin_amdgcn_s_sleep(1);
      it++;
    } else {
      __builtin_amdgcn_s_sleep(4);
    }
    if ((long long)__builtin_amdgcn_s_memrealtime() - t0 > 20000000ll) break;
  }
}
// slow poll for coarse gating (GEMM blocks): ~0.5us quantum
DEVI void poll_slow(unsigned* p, unsigned tgt) {
  long long t0 = (long long)__builtin_amdgcn_s_memrealtime();
  while (__hip_atomic_load(p, __ATOMIC_RELAXED, __HIP_MEMORY_SCOPE_AGENT) <
         tgt) {
    __builtin_amdgcn_s_sleep(16);
    if ((long long)__builtin_amdgcn_s_memrealtime() - t0 > 20000000ll) break;
  }
}

// ---------------- bf16 MFMA GEMM (256-thr standalone) ----------------------
__global__ __launch_bounds__(256) void gemm_bt(
    const u16* __restrict__ A, int lda,
    const u16* __restrict__ Bt, int ldb,
    float* __restrict__ C, int ldc,
    const float* __restrict__ bias, int M, int K, int bf16out) {
  __shared__ u16 As[128 * 32], Bs[128 * 32];
  const int tid = threadIdx.x;
  const int m0 = blockIdx.y * 128, n0 = blockIdx.x * 128;
  const int lane = tid & 63, w = tid >> 6, wm = w >> 1, wn = w & 1;
  const int lr = lane & 15, lk = lane >> 4;
  f32x4 acc[4][4] = {};
  const int r = tid >> 1, cc = (tid & 1) * 16, k8b = (tid & 1) * 2;

  for (int k0 = 0; k0 < K; k0 += 32) {
    {
      long gr = m0 + r;
      u16x8 v0 = {}, v1 = {};
      if (gr < M) {
        const u16* s = A + gr * (long)lda + k0 + cc;
        v0 = *(const u16x8*)s;
        v1 = *(const u16x8*)(s + 8);
      }
      *(u16x8*)&As[swz(r, k8b)] = v0;
      *(u16x8*)&As[swz(r, k8b + 1)] = v1;
    }
    {
      const u16* s = Bt + (long)(n0 + r) * ldb + k0 + cc;
      u16x8 v0 = *(const u16x8*)s;
      u16x8 v1 = *(const u16x8*)(s + 8);
      *(u16x8*)&Bs[swz(r, k8b)] = v0;
      *(u16x8*)&Bs[swz(r, k8b + 1)] = v1;
    }
    __syncthreads();
    bf16x8 af[4], bfr[4];
#pragma unroll
    for (int mi = 0; mi < 4; mi++)
      af[mi] = *(const bf16x8*)&As[swz(wm * 64 + mi * 16 + lr, lk)];
#pragma unroll
    for (int ni = 0; ni < 4; ni++)
      bfr[ni] = *(const bf16x8*)&Bs[swz(wn * 64 + ni * 16 + lr, lk)];
#pragma unroll
    for (int mi = 0; mi < 4; mi++)
#pragma unroll
      for (int ni = 0; ni < 4; ni++)
        acc[mi][ni] = MFMA(af[mi], bfr[ni], acc[mi][ni], 0, 0, 0);
    __syncthreads();
  }
#pragma unroll
  for (int ni = 0; ni < 4; ni++) {
    int col = n0 + wn * 64 + ni * 16 + lr;
    float bs = bias ? bias[col] : 0.f;
#pragma unroll
    for (int mi = 0; mi < 4; mi++) {
#pragma unroll
      for (int rr = 0; rr < 4; rr++) {
        long row = m0 + wm * 64 + mi * 16 + lk * 4 + rr;
        if (row < M) {
          float v = acc[mi][ni][rr] + bs;
          if (bf16out)
            ((u16*)C)[row * (long)ldc + col] = f2bf(v);
          else
            C[row * (long)ldc + col] = v;
        }
      }
    }
  }
}

// 512-thread tile variant (threads 256..511 idle but join barriers)
DEVI void gemm_tile512(const u16* A, int lda, const u16* Bt, int ldb,
                       float* C, int ldc, const float* bias, int M, int K,
                       int mt, int nt) {
  __shared__ u16 As[128 * 32], Bs[128 * 32];
  const int tid = threadIdx.x;
  const bool act = tid < 256;
  const int m0 = mt * 128, n0 = nt * 128;
  const int lane = tid & 63, w = tid >> 6, wm = (w >> 1) & 1, wn = w & 1;
  const int lr = lane & 15, lk = lane >> 4;
  f32x4 acc[4][4] = {};
  const int r = (tid >> 1) & 127, cc = (tid & 1) * 16, k8b = (tid & 1) * 2;

  for (int k0 = 0; k0 < K; k0 += 32) {
    if (act) {
      {
        long gr = m0 + r;
        u16x8 v0 = {}, v1 = {};
        if (gr < M) {
          const u16* s = A + gr * (long)lda + k0 + cc;
          v0 = *(const u16x8*)s;
          v1 = *(const u16x8*)(s + 8);
        }
        *(u16x8*)&As[swz(r, k8b)] = v0;
        *(u16x8*)&As[swz(r, k8b + 1)] = v1;
      }
      {
        const u16* s = Bt + (long)(n0 + r) * ldb + k0 + cc;
        u16x8 v0 = *(const u16x8*)s;
        u16x8 v1 = *(const u16x8*)(s + 8);
        *(u16x8*)&Bs[swz(r, k8b)] = v0;
        *(u16x8*)&Bs[swz(r, k8b + 1)] = v1;
      }
    }
    __syncthreads();
    if (act) {
      bf16x8 af[4], bfr[4];
#pragma unroll
      for (int mi = 0; mi < 4; mi++)
        af[mi] = *(const bf16x8*)&As[swz(wm * 64 + mi * 16 + lr, lk)];
#pragma unroll
      for (int ni = 0; ni < 4; ni++)
        bfr[ni] = *(const bf16x8*)&Bs[swz(wn * 64 + ni * 16 + lr, lk)];
#pragma unroll
      for (int mi = 0; mi < 4; mi++)
#pragma unroll
        for (int ni = 0; ni < 4; ni++)
          acc[mi][ni] = MFMA(af[mi], bfr[ni], acc[mi][ni], 0, 0, 0);
    }
    __syncthreads();
  }
  if (act) {
#pragma unroll
    for (int ni = 0; ni < 4; ni++) {
      int col = n0 + wn * 64 + ni * 16 + lr;
      float bs = bias ? bias[col] : 0.f;
#pragma unroll
      for (int mi = 0; mi < 4; mi++) {
#pragma unroll
        for (int rr = 0; rr < 4; rr++) {
          long row = m0 + wm * 64 + mi * 16 + lk * 4 + rr;
          if (row < M) C[row * (long)ldc + col] = acc[mi][ni][rr] + bs;
        }
      }
    }
  }
}

// ---------------- helpers ---------------------------------------------------
__global__ void zero_f(float* p, long n) {
  long i = (long)blockIdx.x * 256 + threadIdx.x;
  long st = (long)gridDim.x * 256;
  for (; i < n; i += st) p[i] = 0.f;
}

__global__ void zero_u(unsigned* p, int n) {
  int i = blockIdx.x * 256 + threadIdx.x;
  if (i < n) p[i] = 0u;
}

__global__ void cast_bf(const float* __restrict__ src, u16* __restrict__ dst,
                        int ld, int off, int Csz) {
  long row = blockIdx.y;
  int col = blockIdx.x * 256 + threadIdx.x;
  dst[row * Csz + col] = f2bf(src[row * ld + off + col]);
}

// permuted-row cast: dst row n' = src row (g*H + jH), n' = jH*4 + g
__global__ void cast_perm(const float* __restrict__ src, int ld, int off,
                          u16* __restrict__ dst) {
  int np = blockIdx.y;
  int c = blockIdx.x * 256 + threadIdx.x;
  int g = np & 3, jH = np >> 2;
  dst[(size_t)np * H + c] = f2bf(src[(size_t)(g * H + jH) * ld + off + c]);
}

// wdec_p row r = j*4+g, cols [0:512)=wih weighted-part, [512:1024)=whh
__global__ void pack_wdec_p(const float* __restrict__ wih,
                            const float* __restrict__ whh,
                            u16* __restrict__ dst) {
  int r = blockIdx.y;
  int k = blockIdx.x * 256 + threadIdx.x;
  int g = r & 3, j = r >> 2;
  int srow = g * H + j;
  float v = (k < 512) ? wih[(size_t)srow * (2 * H) + 512 + k]
                      : whh[(size_t)srow * H + (k - 512)];
  dst[(size_t)r * 1024 + k] = f2bf(v);
}

__global__ void bias_perm(const float* __restrict__ a,
                          const float* __restrict__ b, float* __restrict__ o) {
  int np = blockIdx.x * 256 + threadIdx.x;
  int g = np & 3, jH = np >> 2;
  int r = g * H + jH;
  o[np] = a[r] + b[r];
}

__global__ void gather_src_emb(const int* __restrict__ src,
                               const float* __restrict__ emb,
                               u16* __restrict__ dst) {
  int row = blockIdx.y;           // row = t*B + b
  int t = row >> 5, b = row & 31;
  int c = blockIdx.x * 256 + threadIdx.x;
  int tok = src[b * S + t];
  dst[(long)row * H + c] = f2bf(emb[(long)tok * H + c]);
}

__global__ void gather_trg_emb(const int* __restrict__ trg,
                               const float* __restrict__ emb,
                               u16* __restrict__ xout) {
  int row = blockIdx.y;           // row = t*B + b, t < 63
  int t = row >> 5, b = row & 31;
  int c = blockIdx.x * 256 + threadIdx.x;
  int tok = trg[b * T + t];
  xout[(long)row * KOUT + 2 * H + c] = f2bf(emb[(long)tok * H + c]);
}

// ---------------- fused encoder launch --------------------------------------
// blocks 0..31: persistent encoder. blocks 32..287: eih GEMM tiles.
// blocks 288..383: outw cast. All co-resident (2/CU at 512 threads).
__global__ __launch_bounds__(512) void enc_fused(
    unsigned* fes, const u16* __restrict__ wenc_p,
    const float* __restrict__ xih_p, u16* hstep, u16* enc_bt_bf, float* cbuf,
    const u16* __restrict__ xoute, const u16* __restrict__ wihE_p,
    float* __restrict__ eih_p, const float* __restrict__ bdec_p,
    const float* __restrict__ out_w, u16* __restrict__ outw_bf) {
  const int bk = blockIdx.x;
  if (bk >= 288) {  // outw cast, grid-stride
    long i = (long)(bk - 288) * 512 + threadIdx.x;
    const long n4 = (long)V * KOUT / 4, st = 96L * 512;
    for (; i < n4; i += st) {
      float4 v = ((const float4*)out_w)[i];
      u16x4 o;
      o[0] = f2bf(v.x); o[1] = f2bf(v.y); o[2] = f2bf(v.z); o[3] = f2bf(v.w);
      *(u16x4*)&outw_bf[i * 4] = o;
    }
    return;
  }
  if (bk >= 32) {  // eih = xout_e @ wihE_p^T + bdec_p
    int job = bk - 32, mt = job >> 4, nt = job & 15;
    gemm_tile512(xoute, KOUT, wihE_p, H, eih_p, H4, bdec_p, MOUT, H, mt, nt);
    return;
  }
  // ---- persistent encoder block ----
  __shared__ float gs[32][64];
  __shared__ float c_s[512];
  __shared__ u16 hx[512];
  const int tid = threadIdx.x;
  const int wave = tid >> 6, lane = tid & 63;
  const int lr = lane & 15, lk = lane >> 4;
  const int bq = tid >> 4, jl = tid & 15;
  c_s[tid] = 0.f;
  const int mt = wave & 1, nt = wave >> 1;
  const int n = nt * 16 + lr;
  bf16x8 wf[16];
  {
    const u16* wp = wenc_p + (size_t)(bk * 64 + n) * 512 + lk * 8;
#pragma unroll
    for (int kt = 0; kt < 16; kt++) wf[kt] = *(const bf16x8*)(wp + kt * 32);
  }
  for (int t = 0; t < S; t++) {
    if (t > 0 && tid < 32) poll_bo(fes + tid * 16, (unsigned)t);
    __syncthreads();
    float4 xv = *(const float4*)(xih_p + ((size_t)t * B + bq) * H4 +
                                 (bk * 16 + jl) * 4);
    {
      const u16* ab =
          hstep + (size_t)t * B * H + (size_t)(mt * 16 + lr) * H + lk * 8;
      f32x4 acc = {};
#pragma unroll
      for (int kt = 0; kt < 16; kt++) {
        bf16x8 a = *(const bf16x8*)(ab + kt * 32);
        acc = MFMA(a, wf[kt], acc, 0, 0, 0);
      }
#pragma unroll
      for (int rr = 0; rr < 4; rr++) gs[mt * 16 + lk * 4 + rr][n] = acc[rr];
    }
    __syncthreads();
    {
      float gi = xv.x + gs[bq][jl * 4 + 0];
      float gf = xv.y + gs[bq][jl * 4 + 1];
      float gg = xv.z + gs[bq][jl * 4 + 2];
      float go = xv.w + gs[bq][jl * 4 + 3];
      float cn = sigm(gf) * c_s[tid] + sigm(gi) * tanh_(gg);
      c_s[tid] = cn;
      u16 h16 = f2bf(sigm(go) * tanh_(cn));
      hx[tid] = h16;
      enc_bt_bf[((size_t)bq * S + t) * H + bk * 16 + jl] = h16;
    }
    __syncthreads();
    u64 kp = 0;
    if (tid < 128) {
      int bb = tid >> 2, q = tid & 3;
      kp = xstore(hstep + (size_t)(t + 1) * B * H + (size_t)bb * H + bk * 16 +
                      q * 4,
                  pack4u(&hx[bb * 16 + q * 4]));
    }
    if (wave < 2) {
      asm volatile("" :: "v"(kp));
      asm volatile("s_waitcnt vmcnt(0)" ::: "memory");
    }
    __syncthreads();
    if (tid == 0) sstore(fes + bk * 16, (unsigned)(t + 1));
  }
  cbuf[bq * H + bk * 16 + jl] = c_s[tid];
}

// ---------------- fused decoder + final GEMM: 160 blocks x 512 -------------
// blocks 0..31: persistent decoder. blocks 32..159: final logits GEMM,
// nt-major (outw slice reused across all 16 mt -> outw read ONCE from HBM),
// each mt flag-gated on fhs.
__global__ __launch_bounds__(512) void dec_fused(
    unsigned* fhs, unsigned* fws, unsigned* fps, const float* __restrict__ fc_w,
    const float* __restrict__ fc_b, const u16* __restrict__ wdec_p,
    const u16* __restrict__ a1_bf, const float* __restrict__ attn_v,
    const int* __restrict__ src, const u16* __restrict__ hf_bf,
    const float* __restrict__ cbuf, const u16* __restrict__ epart_bf,
    const u16* __restrict__ enc_bt_bf, const float* __restrict__ eih_p,
    u16* hstep, u16* wstep, float* hpstep, u16* __restrict__ xout_bf,
    const u16* __restrict__ outw_bf, const float* __restrict__ out_b,
    float* __restrict__ out) {
  const int tid = threadIdx.x, bk = blockIdx.x;
  if (bk >= 32) {
    // ---- final GEMM: logits[2016,32000] = xout @ outw^T + out_b ----
    const int g = bk - 32;            // 0..127
    for (int nt = g; nt < 250; nt += 128) {
      for (int mt = 0; mt < 16; mt++) {
        int tmax = mt * 4 + 3;
        unsigned tgt = (unsigned)((tmax > TD - 1 ? TD - 1 : tmax) + 2);
        if (tid < 32) poll_slow(fhs + tid * 16, tgt);
        __syncthreads();
        gemm_tile512(xout_bf, KOUT, outw_bf, KOUT, out + (size_t)B * V, V,
                     out_b, MOUT, KOUT, mt, nt);
      }
    }
    return;
  }
  // ---- persistent decoder block ----
  __shared__ float buf[8][512];   // weighted partials
  __shared__ float hps[512];
  __shared__ float hp2[32][16];
  __shared__ float gh[32][64];
  __shared__ float gw[32][64];
  __shared__ float sc[128], red[2];
  __shared__ int smask[128];
  __shared__ float c_s[512];
  __shared__ u16 hx[512];
  const int wave = tid >> 6, lane = tid & 63;
  const int lr = lane & 15, lk = lane >> 4;
  const int bq = tid >> 4, jl = tid & 15;
  c_s[tid] = cbuf[bq * H + bk * 16 + jl];
  if (tid < 128) smask[tid] = src[bk * S + tid];
  float av8[8];
#pragma unroll
  for (int e = 0; e < 8; e++) av8[e] = attn_v[lane * 8 + e];
  // fc: hidden = tanh(hf @ fc_w^T + fc_b) -> h[0] slice (waves 0,1)
  if (wave < 2) {
    const u16* ab = hf_bf + (size_t)(wave * 16 + lr) * H + lk * 8;
    const float* frow = fc_w + (size_t)(bk * 16 + lr) * H + lk * 8;
    f32x4 acc = {};
#pragma unroll
    for (int kt = 0; kt < 16; kt++) {
      bf16x8 a = *(const bf16x8*)(ab + kt * 32);
      bf16x8 w;
#pragma unroll
      for (int e = 0; e < 8; e++) w[e] = (short)f2bf(frow[kt * 32 + e]);
      acc = MFMA(a, w, acc, 0, 0, 0);
    }
    float bs = fc_b[bk * 16 + lr];
#pragma unroll
    for (int rr = 0; rr < 4; rr++)
      hx[(wave * 16 + lk * 4 + rr) * 16 + lr] = f2bf(tanh_(acc[rr] + bs));
  }
  __syncthreads();
  {
    u64 kp = 0;
    if (tid < 128) {
      int bb = tid >> 2, q = tid & 3;
      kp = xstore(hstep + (size_t)bb * H + bk * 16 + q * 4,
                  pack4u(&hx[bb * 16 + q * 4]));
    }
    if (wave < 2) {
      asm volatile("" :: "v"(kp));
      asm volatile("s_waitcnt vmcnt(0)" ::: "memory");
    }
    __syncthreads();
    if (tid == 0) sstore(fhs + bk * 16, 1u);
  }
  // gate weight slices; register-cache the w-part (post-poll path)
  const int mt = wave & 1, nt = wave >> 1;
  const int n = nt * 16 + lr;
  const u16* wpw = wdec_p + (size_t)(bk * 64 + n) * 1024 + lk * 8;
  const u16* wph = wpw + 512;
  bf16x8 wwf[16];
#pragma unroll
  for (int kt = 0; kt < 16; kt++) wwf[kt] = *(const bf16x8*)(wpw + kt * 32);
  // ---- time loop ----
  for (int t = 0; t < TD; t++) {
    if (tid < 32) poll_bo(fhs + tid * 16, (unsigned)(t + 1));
    __syncthreads();
    float4 xv = *(const float4*)(eih_p + ((size_t)t * B + bq) * H4 +
                                 (bk * 16 + jl) * 4);
    // --- gates_h (all waves) ---
    {
      const u16* ah =
          hstep + (size_t)t * B * H + (size_t)(mt * 16 + lr) * H + lk * 8;
      f32x4 acc = {};
#pragma unroll
      for (int kt = 0; kt < 16; kt++) {
        bf16x8 a = *(const bf16x8*)(ah + kt * 32);
        bf16x8 w = *(const bf16x8*)(wph + kt * 32);
        acc = MFMA(a, w, acc, 0, 0, 0);
      }
#pragma unroll
      for (int rr = 0; rr < 4; rr++) gh[mt * 16 + lk * 4 + rr][n] = acc[rr];
    }
    // --- hp n-shard: hp[all b][bk*16+lr] = h @ a1-slice (waves 0,1) ---
    if (wave < 2) {
      const u16* ah =
          hstep + (size_t)t * B * H + (size_t)(wave * 16 + lr) * H + lk * 8;
      const u16* bp = a1_bf + (size_t)(bk * 16 + lr) * 512 + lk * 8;
      f32x4 acc = {};
#pragma unroll
      for (int kt = 0; kt < 16; kt++) {
        bf16x8 a = *(const bf16x8*)(ah + kt * 32);
        bf16x8 w = *(const bf16x8*)(bp + kt * 32);
        acc = MFMA(a, w, acc, 0, 0, 0);
      }
#pragma unroll
      for (int rr = 0; rr < 4; rr++)
        hp2[wave * 16 + lk * 4 + rr][lr] = acc[rr];
    }
    __syncthreads();
    // publish hp shard (f32 pairs as u64)
    {
      u64 kp = 0;
      if (tid < 256) {
        int b = tid >> 3, ql = tid & 7;
        u64 pk = (u64)__float_as_uint(hp2[b][ql * 2]) |
                 ((u64)__float_as_uint(hp2[b][ql * 2 + 1]) << 32);
        kp = xstore64(
            (u64*)(hpstep + ((size_t)t * B + b) * 512 + bk * 16 + ql * 2), pk);
      }
      if (wave < 4) {
        asm volatile("" :: "v"(kp));
        asm volatile("s_waitcnt vmcnt(0)" ::: "memory");
      }
      __syncthreads();
      if (tid == 0) sstore(fps + bk * 16, (unsigned)(t + 1));
    }
    if (tid < 32) poll_bo(fps + tid * 16, (unsigned)(t + 1));
    __syncthreads();
    hps[tid] = hpstep[((size_t)t * B + bk) * 512 + tid];
    __syncthreads();
    // --- scores: wave w covers s in [w*16, w*16+16) ---
    {
      const int j0 = lane * 8;
      float hp8[8];
#pragma unroll
      for (int e = 0; e < 8; e++) hp8[e] = hps[j0 + e];
#pragma unroll 4
      for (int i = 0; i < 16; i++) {
        int s = wave * 16 + i;
        u16x8 ep = *(const u16x8*)&epart_bf[((size_t)bk * S + s) * H + j0];
        float a = 0.f;
#pragma unroll
        for (int e = 0; e < 8; e++) a += av8[e] * tanhf_(hp8[e] + bf2f(ep[e]));
#pragma unroll
        for (int o = 32; o; o >>= 1) a += __shfl_xor(a, o);
        if (lane == 0) sc[s] = (smask[s] == PAD_IDX) ? -1e10f : a;
      }
    }
    __syncthreads();
    // softmax without max-subtraction (scores bounded by sum|v| ~ 20)
    if (tid < 64) {
      float e0 = __expf(sc[tid]), e1 = __expf(sc[tid + 64]);
      sc[tid] = e0;
      sc[tid + 64] = e1;
      float v = e0 + e1;
#pragma unroll
      for (int o = 32; o; o >>= 1) v += __shfl_xor(v, o);
      if (tid == 0) red[1] = 1.f / v;
    }
    __syncthreads();
    {  // weighted partials: wave w owns s in [w*16, w*16+16)
      float acc8[8] = {};
      const int j0 = lane * 8;
#pragma unroll 4
      for (int i = 0; i < 16; i++) {
        int s = wave * 16 + i;
        float ps = sc[s];
        u16x8 ev = *(const u16x8*)&enc_bt_bf[((size_t)bk * S + s) * H + j0];
#pragma unroll
        for (int e = 0; e < 8; e++) acc8[e] += ps * bf2f(ev[e]);
      }
#pragma unroll
      for (int e = 0; e < 8; e++) buf[wave][j0 + e] = acc8[e];
    }
    __syncthreads();
    {  // finalize + publish w (own batch); xout w write is write-through too
      u64 kp = 0;
      if (tid < 128) {
        float inv = red[1];
        int j0 = tid * 4;
        u16x4 o;
#pragma unroll
        for (int i = 0; i < 4; i++) {
          float wj = (buf[0][j0 + i] + buf[1][j0 + i] + buf[2][j0 + i] +
                      buf[3][j0 + i] + buf[4][j0 + i] + buf[5][j0 + i] +
                      buf[6][j0 + i] + buf[7][j0 + i]) *
                     inv;
          o[i] = f2bf(wj);
        }
        u64 val = (u64)o[0] | ((u64)o[1] << 16) | ((u64)o[2] << 32) |
                  ((u64)o[3] << 48);
        kp = xstore(wstep + ((size_t)t * B + bk) * H + j0, val);
        kp ^= xstore(&xout_bf[((size_t)t * B + bk) * KOUT + H + j0], val);
      }
      if (wave < 2) {
        asm volatile("" :: "v"(kp));
        asm volatile("s_waitcnt vmcnt(0)" ::: "memory");
      }
      __syncthreads();
      if (tid == 0) sstore(fws + bk * 16, (unsigned)(t + 1));
    }
    // --- gates_w: M=32, N=64, K=512 (B-frags in registers) ---
    if (tid < 32) poll_bo(fws + tid * 16, (unsigned)(t + 1));
    __syncthreads();
    {
      const u16* aw =
          wstep + (size_t)t * B * H + (size_t)(mt * 16 + lr) * H + lk * 8;
      f32x4 acc = {};
#pragma unroll
      for (int kt = 0; kt < 16; kt++) {
        bf16x8 a = *(const bf16x8*)(aw + kt * 32);
        acc = MFMA(a, wwf[kt], acc, 0, 0, 0);
      }
#pragma unroll
      for (int rr = 0; rr < 4; rr++) gw[mt * 16 + lk * 4 + rr][n] = acc[rr];
    }
    __syncthreads();
    {  // pointwise
      float gi = xv.x + gh[bq][jl * 4 + 0] + gw[bq][jl * 4 + 0];
      float gf = xv.y + gh[bq][jl * 4 + 1] + gw[bq][jl * 4 + 1];
      float gg = xv.z + gh[bq][jl * 4 + 2] + gw[bq][jl * 4 + 2];
      float go = xv.w + gh[bq][jl * 4 + 3] + gw[bq][jl * 4 + 3];
      float cn = sigm(gf) * c_s[tid] + sigm(gi) * tanh_(gg);
      c_s[tid] = cn;
      u16 h16 = f2bf(sigm(go) * tanh_(cn));
      hx[tid] = h16;
    }
    __syncthreads();
    {  // publish h slice (hstep + xout, both write-through, one vmcnt)
      u64 kp = 0;
      if (tid < 128) {
        int bb = tid >> 2, q = tid & 3;
        u64 hv = pack4u(&hx[bb * 16 + q * 4]);
        kp = xstore(hstep + (size_t)(t + 1) * B * H + (size_t)bb * H +
                        bk * 16 + q * 4,
                    hv);
        kp ^= xstore(&xout_bf[((size_t)t * B + bb) * KOUT + bk * 16 + q * 4],
                     hv);
      }
      if (wave < 2) {
        asm volatile("" :: "v"(kp));
        asm volatile("s_waitcnt vmcnt(0)" ::: "memory");
      }
      __syncthreads();
      if (tid == 0) sstore(fhs + bk * 16, (unsigned)(t + 2));
    }
  }
}

// ---------------------------------------------------------------------------
extern "C" void kernel_launch(void* const* d_in, const int* in_sizes, int n_in,
                              void* d_out, int out_size, void* d_ws,
                              size_t ws_size, hipStream_t stream) {
  const int* src = (const int*)d_in[0];
  const int* trg = (const int*)d_in[2];
  const float* enc_emb = (const float*)d_in[3];
  const float* enc_wih = (const float*)d_in[4];
  const float* enc_whh = (const float*)d_in[5];
  const float* enc_bih = (const float*)d_in[6];
  const float* enc_bhh = (const float*)d_in[7];
  const float* fc_w = (const float*)d_in[8];
  const float* fc_b = (const float*)d_in[9];
  const float* dec_emb = (const float*)d_in[10];
  const float* attn_w = (const float*)d_in[11];
  const float* attn_b = (const float*)d_in[12];
  const float* attn_v = (const float*)d_in[13];
  const float* dec_wih = (const float*)d_in[14];
  const float* dec_whh = (const float*)d_in[15];
  const float* dec_bih = (const float*)d_in[16];
  const float* dec_bhh = (const float*)d_in[17];
  const float* out_w = (const float*)d_in[18];
  const float* out_b = (const float*)d_in[19];
  float* out = (float*)d_out;

  char* wp = (char*)d_ws;
  auto alloc = [&](size_t n) {
    char* p = wp;
    wp += (n + 255) & ~(size_t)255;
    return p;
  };
  u16* outw_bf = (u16*)alloc((size_t)V * KOUT * 2);        // 98.3 MB
  u16* wihenc_p = (u16*)alloc((size_t)H4 * H * 2);         // 2.1 MB
  u16* wihE_p = (u16*)alloc((size_t)H4 * H * 2);           // 2.1 MB
  u16* wenc_p = (u16*)alloc((size_t)H4 * H * 2);           // 2.1 MB
  u16* wdec_p = (u16*)alloc((size_t)H4 * 2 * H * 2);       // 8.4 MB
  u16* attnw2_bf = (u16*)alloc((size_t)H * H * 2);         // 0.5 MB
  u16* a1_bf = (u16*)alloc((size_t)H * H * 2);             // 0.5 MB
  u16* xemb_bf = (u16*)alloc((size_t)S * B * H * 2);       // 4.2 MB
  float* xih_p = (float*)alloc((size_t)S * B * H4 * 4);    // 33.6 MB
  u16* enc_bt_bf = (u16*)alloc((size_t)B * S * H * 2);     // 4.2 MB
  u16* epart_bf = (u16*)alloc((size_t)B * S * H * 2);      // 4.2 MB
  float* eih_p = (float*)alloc((size_t)MOUT * H4 * 4);     // 16.5 MB
  u16* xout_bf = (u16*)alloc((size_t)MOUT * KOUT * 2);     // 6.2 MB
  u16* hstep_enc = (u16*)alloc((size_t)(S + 1) * B * H * 2);  // 4.3 MB
  u16* hstep_dec = (u16*)alloc((size_t)T * B * H * 2);        // 2.1 MB
  u16* wstep = (u16*)alloc((size_t)TD * B * H * 2);           // 2.1 MB
  float* hpstep = (float*)alloc((size_t)TD * B * H * 4);      // 4.1 MB
  float* cbuf = (float*)alloc((size_t)B * H * 4);
  float* benc_p = (float*)alloc((size_t)H4 * 4);
  float* bdec_p = (float*)alloc((size_t)H4 * 4);
  unsigned* flags = (unsigned*)alloc(2048 * 4);
  unsigned* fes = flags;            // 32 slots x 16 u32
  unsigned* fhs = flags + 512;      // 32 slots x 16 u32
  unsigned* fws = flags + 1024;     // 32 slots x 16 u32
  unsigned* fps = flags + 1536;     // 32 slots x 16 u32

  dim3 blk(256);
  zero_f<<<dim3(256), blk, 0, stream>>>(out, (long)B * V);
  zero_u<<<dim3(8), blk, 0, stream>>>(flags, 2048);
  zero_u<<<dim3(32), blk, 0, stream>>>((unsigned*)hstep_enc, B * H / 2);
  // weight preparation (outw cast + eih GEMM fused into enc launch)
  cast_perm<<<dim3(H / 256, H4), blk, 0, stream>>>(enc_wih, H, 0, wihenc_p);
  cast_perm<<<dim3(H / 256, H4), blk, 0, stream>>>(dec_wih, 2 * H, 0, wihE_p);
  cast_perm<<<dim3(H / 256, H4), blk, 0, stream>>>(enc_whh, H, 0, wenc_p);
  pack_wdec_p<<<dim3(4, H4), blk, 0, stream>>>(dec_wih, dec_whh, wdec_p);
  cast_bf<<<dim3(H / 256, H), blk, 0, stream>>>(attn_w, attnw2_bf, 2 * H, H, H);
  cast_bf<<<dim3(H / 256, H), blk, 0, stream>>>(attn_w, a1_bf, 2 * H, 0, H);
  bias_perm<<<dim3(H4 / 256), blk, 0, stream>>>(enc_bih, enc_bhh, benc_p);
  bias_perm<<<dim3(H4 / 256), blk, 0, stream>>>(dec_bih, dec_bhh, bdec_p);
  gather_src_emb<<<dim3(H / 256, S * B), blk, 0, stream>>>(src, enc_emb,
                                                           xemb_bf);
  gather_trg_emb<<<dim3(H / 256, MOUT), blk, 0, stream>>>(trg, dec_emb,
                                                          xout_bf);
  // xih GEMM (encoder consumes it from step 0)
  gemm_bt<<<dim3(H4 / 128, (S * B) / 128), blk, 0, stream>>>(
      xemb_bf, H, wihenc_p, H, xih_p, H4, benc_p, S * B, H, 0);
  // fused: encoder + eih GEMM + outw cast
  enc_fused<<<dim3(384), dim3(512), 0, stream>>>(
      fes, wenc_p, xih_p, hstep_enc, enc_bt_bf, cbuf, xout_bf + 2 * H, wihE_p,
      eih_p, bdec_p, out_w, outw_bf);
  // epart = enc_bt @ attn_w2^T + attn_b  (bf16 out, pre-dec)
  gemm_bt<<<dim3(H / 128, (B * S) / 128), blk, 0, stream>>>(
      enc_bt_bf, H, attnw2_bf, H, (float*)epart_bf, H, attn_b, B * S, H, 1);
  // fused: persistent decoder + final logits GEMM (nt-major, flag-gated)
  dec_fused<<<dim3(160), dim3(512), 0, stream>>>(
      fhs, fws, fps, fc_w, fc_b, wdec_p, a1_bf, attn_v, src,
      hstep_enc + (size_t)S * B * H, cbuf, epart_bf, enc_bt_bf, eih_p,
      hstep_dec, wstep, hpstep, xout_bf, outw_bf, out_b, out);
}